// Round 7
// baseline (188.426 us; speedup 1.0000x reference)
//
#include <hip/hip_runtime.h>
#include <cstdint>
#include <cstddef>

#define NUM_LAYERS 20
#define HID 1024
#define M_TOTAL 8192

typedef __attribute__((ext_vector_type(8))) short bf16x8;
typedef __attribute__((ext_vector_type(4))) float floatx4;
typedef __attribute__((ext_vector_type(4))) float f32x4;
typedef __attribute__((ext_vector_type(8))) unsigned short u16x8;

typedef __attribute__((address_space(1))) unsigned int as1_u32;
typedef __attribute__((address_space(3))) unsigned int as3_u32;

__device__ __forceinline__ unsigned short f2bf(float f) {
  union { float f; unsigned int u; } v; v.f = f;
  unsigned int r = v.u + 0x7fffu + ((v.u >> 16) & 1u);  // RNE
  return (unsigned short)(r >> 16);
}

__device__ __forceinline__ float bf2f(unsigned short u) {
  union { unsigned int u; float f; } v; v.u = ((unsigned int)u) << 16;
  return v.f;
}

__device__ __forceinline__ u16x8 pack8(f32x4 a, f32x4 b) {
  u16x8 o;
  o[0] = f2bf(a[0]); o[1] = f2bf(a[1]); o[2] = f2bf(a[2]); o[3] = f2bf(a[3]);
  o[4] = f2bf(b[0]); o[5] = f2bf(b[1]); o[6] = f2bf(b[2]); o[7] = f2bf(b[3]);
  return o;
}

// async global->LDS, 16B/lane; LDS ptr must be wave-uniform base (HW adds lane*16)
__device__ __forceinline__ void load16_lds(const void* g, void* l) {
  __builtin_amdgcn_global_load_lds(
      reinterpret_cast<as1_u32*>(reinterpret_cast<uintptr_t>(g)),
      reinterpret_cast<as3_u32*>(reinterpret_cast<uintptr_t>(l)),
      16, 0, 0);
}

// ---- Kernel 1: conv_w 20-layer sum -> bf16 wb [N][K] row-major (proven).
// 40 float4 NT loads in flight/thread; HBM-bound ~85% on the 80 MB read.
// (x-cast half of the old prep_kernel is now fused into the GEMM's A-staging,
// deleting the 16 MB xb write + 16 MB re-read.)
__global__ __launch_bounds__(256, 1) void wsum_kernel(const float* __restrict__ w,
                                                      unsigned short* __restrict__ wb) {
  const int P = blockIdx.x * 256 + threadIdx.x;  // ushort8 output index
  const f32x4* p = reinterpret_cast<const f32x4*>(w);
  f32x4 va[NUM_LAYERS], vb[NUM_LAYERS];
#pragma unroll
  for (int l = 0; l < NUM_LAYERS; ++l) {
    const f32x4* pl = p + (size_t)l * (HID * HID / 4) + (size_t)2 * P;
    va[l] = __builtin_nontemporal_load(pl);
    vb[l] = __builtin_nontemporal_load(pl + 1);
  }
  f32x4 s0 = va[0], s1 = vb[0];
#pragma unroll
  for (int l = 1; l < NUM_LAYERS; ++l) { s0 += va[l]; s1 += vb[l]; }
  reinterpret_cast<u16x8*>(wb)[P] = pack8(s0, s1);
}

// ---- Kernel 2: GEMM C[M][N] = bf16(x)[M][K] @ B[N][K]^T, fp32 A in, bf16 out.
// m97 geometry: 128x128 tile, BK=64, 256 threads = 4 waves (2M x 2N), wave tile
// 64x64 (4x4 of 16x16x32 MFMA x 2 k-halves). Grid 64x8 = 512 = 2 blocks/CU,
// all 64 blocks of an XCD co-resident (mb=bid&63 -> same-A blocks share XCD;
// panel read 8x but temporally clustered -> L2-served, HBM-fetched once).
// Round-6 deltas:
//  (a) A staged from fp32 x via regs + RNE cvt + ds_write (kills xb round-trip);
//      A-loads for t+1 issued right after the barrier, hidden under MFMA (T14).
//  (b) slot-XOR LDS swizzle phys16Bslot = slot ^ (row&7) on BOTH tiles:
//      without it, BK=64 rows (128 B) make each quarter-wave ds_read_b128 a
//      16-way bank conflict (~5.69x, m136). B keeps global_load_lds with the
//      source address pre-swizzled (linear dest; both-sides-or-neither).
__global__ __launch_bounds__(256, 2) void gemm_kernel(const float* __restrict__ x,
                                                      const unsigned short* __restrict__ B,
                                                      unsigned short* __restrict__ Cb) {
  __shared__ unsigned short lA[128 * 64];  // 16 KiB
  __shared__ unsigned short lB[128 * 64];  // 16 KiB

  const int tid = threadIdx.x;
  const int lane = tid & 63;
  const int w = tid >> 6;      // wave 0..3
  const int wr = w >> 1;       // 0..1 -> M half
  const int wc = w & 1;        // 0..1 -> N half
  const int quad = lane >> 4;  // 0..3
  const int mrow = lane & 15;

  const int bid = blockIdx.x;
  const int mb = bid & 63;  // 64 M-tiles; same-A blocks share an XCD
  const int nb = bid >> 6;  // 8 N-tiles
  const int m0 = mb * 128;
  const int n0 = nb * 128;

  // Staging geometry: per issue i (0..3), thread t covers row r = i*32 + (t>>3),
  // logical 16B-slot (t&7) of the 8-slot (128 B) row. Physical slot = logical
  // XOR (r&7); i*32 is 0 mod 8 so the key is (t>>3)&7, issue-invariant.
  const int srow = tid >> 3;                 // 0..31
  const int skslot = tid & 7;                // logical slot
  const int sphys = skslot ^ (srow & 7);     // physical slot
  // B: global_load_lds dest is linear (byte = i*4096 + t*16 -> row r, phys slot
  // t&7); content must be logical slot (t&7)^(r&7) -> pre-swizzled SOURCE:
  const unsigned short* gB = B + (size_t)(n0 + srow) * HID + sphys * 8;
  // A: fp32 source at the thread's LOGICAL slot; ds_write to the physical slot.
  const float* gA = x + (size_t)(m0 + srow) * HID + skslot * 8;
  unsigned short* dA = lA + srow * 64 + sphys * 8;  // + i*2048 per issue
  unsigned short* dB = lB + w * 512;                // wave-uniform, + i*2048

  floatx4 acc[4][4] = {};
  f32x4 Ar[8];

  // Fragment read bases; swizzled k-offset: slot = kk*4+quad, key = mrow&7
  // (frag rows are wr*64 + i*16 + mrow -> row&7 == mrow&7).
  const int offk0 = ((quad ^ (mrow & 7)) << 3);  // kk=0; kk=1 is offk0 ^ 32
  const unsigned short* ra[4];
  const unsigned short* rb[4];
#pragma unroll
  for (int i = 0; i < 4; ++i)
    ra[i] = lA + (wr * 64 + i * 16 + mrow) * 64;
#pragma unroll
  for (int j = 0; j < 4; ++j)
    rb[j] = lB + (wc * 64 + j * 16 + mrow) * 64;

#define LOADA(k0)                                                              \
  {                                                                            \
    _Pragma("unroll") for (int i = 0; i < 4; ++i) {                            \
      const float* s = gA + (size_t)(i * 32) * HID + (k0);                     \
      Ar[2 * i]     = *reinterpret_cast<const f32x4*>(s);                      \
      Ar[2 * i + 1] = *reinterpret_cast<const f32x4*>(s + 4);                  \
    }                                                                          \
  }

  LOADA(0);

  for (int t = 0; t < 16; ++t) {
    const int k0 = t * 64;
    __syncthreads();  // waves done reading LDS from step t-1 (also drains Ar)
#pragma unroll
    for (int i = 0; i < 4; ++i)
      load16_lds(gB + (size_t)(i * 32) * HID + k0, dB + i * 2048);
#pragma unroll
    for (int i = 0; i < 4; ++i)
      *reinterpret_cast<u16x8*>(dA + i * 2048) = pack8(Ar[2 * i], Ar[2 * i + 1]);
    __syncthreads();  // drains B gloads (vmcnt) + A writes (lgkm)

    if (t < 15) LOADA(k0 + 64);  // T14: issue early, hide under MFMA phase

#pragma unroll
    for (int kk = 0; kk < 2; ++kk) {
      const int off = offk0 ^ (kk << 5);
      bf16x8 af[4], bfr[4];
#pragma unroll
      for (int i = 0; i < 4; ++i)
        af[i] = *reinterpret_cast<const bf16x8*>(ra[i] + off);
#pragma unroll
      for (int j = 0; j < 4; ++j)
        bfr[j] = *reinterpret_cast<const bf16x8*>(rb[j] + off);
#pragma unroll
      for (int i = 0; i < 4; ++i)
#pragma unroll
        for (int j = 0; j < 4; ++j)
          acc[i][j] = __builtin_amdgcn_mfma_f32_16x16x32_bf16(af[i], bfr[j], acc[i][j], 0, 0, 0);
    }
  }
#undef LOADA

  // epilogue: verified C/D mapping: out row = quad*4 + r, out col = mrow.
  const int row_base = m0 + wr * 64 + quad * 4;
  const int col_base = n0 + wc * 64 + mrow;
#pragma unroll
  for (int i = 0; i < 4; ++i) {
#pragma unroll
    for (int j = 0; j < 4; ++j) {
#pragma unroll
      for (int r = 0; r < 4; ++r) {
        int row = row_base + i * 16 + r;
        Cb[(size_t)row * HID + col_base + j * 16] = f2bf(acc[i][j][r]);
      }
    }
  }
}

// ---- Kernel 3: RMS norm (proven; ~9 us, near its 7.6 us floor) ----
// out = C * 32 * rsqrt(sum C^2 + 400*eps*H) * norm_w   (/20 folded into scale)
__global__ __launch_bounds__(256) void rmsnorm_kernel(const unsigned short* __restrict__ Cb,
                                                      const float* __restrict__ nw,
                                                      float* __restrict__ out) {
  const int row = blockIdx.x * 4 + (threadIdx.x >> 6);
  const int lane = threadIdx.x & 63;
  const u16x8* src = reinterpret_cast<const u16x8*>(Cb) + (size_t)row * 128;
  f32x4 v[2][2];
  float ss = 0.f;
#pragma unroll
  for (int j = 0; j < 2; ++j) {
    u16x8 u = src[lane + j * 64];
#pragma unroll
    for (int h = 0; h < 2; ++h) {
#pragma unroll
      for (int e = 0; e < 4; ++e) {
        float f = bf2f(u[h * 4 + e]);
        v[j][h][e] = f;
        ss += f * f;
      }
    }
  }
#pragma unroll
  for (int off = 32; off > 0; off >>= 1) ss += __shfl_xor(ss, off, 64);
  const float scale = 32.0f * rsqrtf(ss + 0.4096f);  // 32=sqrt(H); 0.4096 = eps*H*400
  const f32x4* nwp = reinterpret_cast<const f32x4*>(nw);
  f32x4* dst = reinterpret_cast<f32x4*>(out) + (size_t)row * 256;
#pragma unroll
  for (int j = 0; j < 2; ++j) {
#pragma unroll
    for (int h = 0; h < 2; ++h) {
      const int fi = 2 * (lane + j * 64) + h;
      f32x4 wv = nwp[fi];
      f32x4 o = v[j][h] * scale * wv;
      __builtin_nontemporal_store(o, dst + fi);
    }
  }
}

extern "C" void kernel_launch(void* const* d_in, const int* in_sizes, int n_in,
                              void* d_out, int out_size, void* d_ws, size_t ws_size,
                              hipStream_t stream) {
  const float* x = (const float*)d_in[0];       // [2,4096,1024] fp32
  const float* conv_w = (const float*)d_in[1];  // [20,1024,1024] fp32
  const float* norm_w = (const float*)d_in[2];  // [1024] fp32
  float* out = (float*)d_out;                   // [2,4096,1024] fp32

  unsigned short* wb = (unsigned short*)d_ws;   // 2 MiB: summed W bf16 [N][K]
  unsigned short* cb = wb + (size_t)HID * HID;  // +16 MiB: C bf16

  wsum_kernel<<<512, 256, 0, stream>>>(conv_w, wb);
  gemm_kernel<<<(M_TOTAL / 128) * (HID / 128), 256, 0, stream>>>(x, wb, cb);
  rmsnorm_kernel<<<M_TOTAL / 4, 256, 0, stream>>>(cb, norm_w, out);
}

// Round 8
// 182.253 us; speedup vs baseline: 1.0339x; 1.0339x over previous
//
#include <hip/hip_runtime.h>
#include <cstdint>
#include <cstddef>

#define NUM_LAYERS 20
#define HID 1024
#define M_TOTAL 8192

typedef __attribute__((ext_vector_type(8))) short bf16x8;
typedef __attribute__((ext_vector_type(4))) float floatx4;
typedef __attribute__((ext_vector_type(4))) float f32x4;
typedef __attribute__((ext_vector_type(8))) unsigned short u16x8;

typedef __attribute__((address_space(1))) unsigned int as1_u32;
typedef __attribute__((address_space(3))) unsigned int as3_u32;

__device__ __forceinline__ unsigned short f2bf(float f) {
  union { float f; unsigned int u; } v; v.f = f;
  unsigned int r = v.u + 0x7fffu + ((v.u >> 16) & 1u);  // RNE
  return (unsigned short)(r >> 16);
}

__device__ __forceinline__ float bf2f(unsigned short u) {
  union { unsigned int u; float f; } v; v.u = ((unsigned int)u) << 16;
  return v.f;
}

__device__ __forceinline__ u16x8 pack8(f32x4 a, f32x4 b) {
  u16x8 o;
  o[0] = f2bf(a[0]); o[1] = f2bf(a[1]); o[2] = f2bf(a[2]); o[3] = f2bf(a[3]);
  o[4] = f2bf(b[0]); o[5] = f2bf(b[1]); o[6] = f2bf(b[2]); o[7] = f2bf(b[3]);
  return o;
}

// async global->LDS, 16B/lane; LDS ptr must be wave-uniform base (HW adds lane*16)
__device__ __forceinline__ void load16_lds(const void* g, void* l) {
  __builtin_amdgcn_global_load_lds(
      reinterpret_cast<as1_u32*>(reinterpret_cast<uintptr_t>(g)),
      reinterpret_cast<as3_u32*>(reinterpret_cast<uintptr_t>(l)),
      16, 0, 0);
}

// ---- Kernel 1: conv_w 20-layer sum -> bf16 wb [N][K] row-major (proven).
// 40 float4 NT loads in flight/thread; HBM-bound ~85% on the 80 MB read.
__global__ __launch_bounds__(256, 1) void wsum_kernel(const float* __restrict__ w,
                                                      unsigned short* __restrict__ wb) {
  const int P = blockIdx.x * 256 + threadIdx.x;  // ushort8 output index
  const f32x4* p = reinterpret_cast<const f32x4*>(w);
  f32x4 va[NUM_LAYERS], vb[NUM_LAYERS];
#pragma unroll
  for (int l = 0; l < NUM_LAYERS; ++l) {
    const f32x4* pl = p + (size_t)l * (HID * HID / 4) + (size_t)2 * P;
    va[l] = __builtin_nontemporal_load(pl);
    vb[l] = __builtin_nontemporal_load(pl + 1);
  }
  f32x4 s0 = va[0], s1 = vb[0];
#pragma unroll
  for (int l = 1; l < NUM_LAYERS; ++l) { s0 += va[l]; s1 += vb[l]; }
  reinterpret_cast<u16x8*>(wb)[P] = pack8(s0, s1);
}

// ---- Kernel 2: GEMM C[M][N] = bf16(x)[M][K] @ B[N][K]^T, fp32 A in, bf16 out.
// 128x128 tile, BK=64, 256 threads = 4 waves (2M x 2N), wave tile 64x64.
// Grid 64x8 = 512 = 2 blocks/CU; mb=bid&63 clusters same-A blocks on one XCD.
// Round-7 post-mortem: two barriers per K-step, with B's global_load_lds
// issued and immediately drained inside the same barrier pair -> ~200-300 cy
// L2 latency exposed 16x, plus 32 barrier drains. Round-8: T3-minimum
// schedule (m230/m248): double-buffered LDS, ONE barrier per K-step:
//   ds_read frags(cur) -> stageB(nxt)+writeA(nxt) -> loadA(t+2) -> MFMA -> bar
// B's loads get the whole ds_read+MFMA phase to land; A regs get a full
// iteration (T14). Slot-XOR swizzle kept (phys16Bslot = slot ^ (row&7),
// both-sides: pre-swizzled gload source / swizzled ds_write + ds_read).
__global__ __launch_bounds__(256, 2) void gemm_kernel(const float* __restrict__ x,
                                                      const unsigned short* __restrict__ B,
                                                      unsigned short* __restrict__ Cb) {
  __shared__ unsigned short lA[2][128 * 64];  // 2 x 16 KiB
  __shared__ unsigned short lB[2][128 * 64];  // 2 x 16 KiB

  const int tid = threadIdx.x;
  const int lane = tid & 63;
  const int w = tid >> 6;      // wave 0..3
  const int wr = w >> 1;       // 0..1 -> M half
  const int wc = w & 1;        // 0..1 -> N half
  const int quad = lane >> 4;  // 0..3
  const int mrow = lane & 15;

  const int bid = blockIdx.x;
  const int mb = bid & 63;  // 64 M-tiles; same-A blocks share an XCD
  const int nb = bid >> 6;  // 8 N-tiles
  const int m0 = mb * 128;
  const int n0 = nb * 128;

  // Staging geometry: issue i covers row r = i*32 + (t>>3), logical 16B-slot
  // (t&7) of the 128 B row; physical slot = logical ^ (r&7).
  const int srow = tid >> 3;                 // 0..31
  const int skslot = tid & 7;                // logical slot
  const int sphys = skslot ^ (srow & 7);     // physical slot
  // B: linear gload_lds dest; content pre-swizzled at the SOURCE.
  const unsigned short* gB = B + (size_t)(n0 + srow) * HID + sphys * 8;
  // A: fp32 source at the LOGICAL slot; ds_write to the physical slot.
  const float* gA = x + (size_t)(m0 + srow) * HID + skslot * 8;
  unsigned short* dA = &lA[0][0] + srow * 64 + sphys * 8;  // + i*2048 per issue
  unsigned short* dB = &lB[0][0] + w * 512;                // wave-uniform

  floatx4 acc[4][4] = {};
  f32x4 Ar[8];

  // Fragment read bases (buffer 0); swizzled k-offset: slot = kk*4+quad,
  // key = mrow&7 (frag row & 7 == mrow & 7).
  const int offk0 = ((quad ^ (mrow & 7)) << 3);  // kk=0; kk=1 is offk0 ^ 32
  const unsigned short* ra[4];
  const unsigned short* rb[4];
#pragma unroll
  for (int i = 0; i < 4; ++i)
    ra[i] = &lA[0][0] + (wr * 64 + i * 16 + mrow) * 64;
#pragma unroll
  for (int j = 0; j < 4; ++j)
    rb[j] = &lB[0][0] + (wc * 64 + j * 16 + mrow) * 64;

#define LOADA(k0)                                                              \
  {                                                                            \
    _Pragma("unroll") for (int i = 0; i < 4; ++i) {                            \
      const float* s = gA + (size_t)(i * 32) * HID + (k0);                     \
      Ar[2 * i]     = *reinterpret_cast<const f32x4*>(s);                      \
      Ar[2 * i + 1] = *reinterpret_cast<const f32x4*>(s + 4);                  \
    }                                                                          \
  }
#define STAGEB(bufofs, k0)                                                     \
  {                                                                            \
    _Pragma("unroll") for (int i = 0; i < 4; ++i)                              \
        load16_lds(gB + (size_t)(i * 32) * HID + (k0),                         \
                   dB + (bufofs) + i * 2048);                                  \
  }
#define WRITEA(bufofs)                                                         \
  {                                                                            \
    _Pragma("unroll") for (int i = 0; i < 4; ++i)                              \
        *reinterpret_cast<u16x8*>(dA + (bufofs) + i * 2048) =                  \
            pack8(Ar[2 * i], Ar[2 * i + 1]);                                   \
  }

  // Prologue: buffer 0 staged for t=0; A regs for t=1 in flight.
  LOADA(0);
  STAGEB(0, 0);
  WRITEA(0);
  LOADA(64);
  __syncthreads();

  for (int t = 0; t < 16; ++t) {
    const int cur = t & 1;
    const int cofs = cur << 13;         // cur * 8192 ushorts
    const int nofs = cofs ^ 8192;       // nxt buffer offset

    // 1) issue this step's fragment reads first (MFMA waits only on these;
    //    later DS-writes don't gate them).
    bf16x8 af[2][4], bfr[2][4];
#pragma unroll
    for (int kk = 0; kk < 2; ++kk) {
      const int off = offk0 ^ (kk << 5);
#pragma unroll
      for (int i = 0; i < 4; ++i)
        af[kk][i] = *reinterpret_cast<const bf16x8*>(ra[i] + cofs + off);
#pragma unroll
      for (int j = 0; j < 4; ++j)
        bfr[kk][j] = *reinterpret_cast<const bf16x8*>(rb[j] + cofs + off);
    }

    // 2) stage step t+1 into the other buffer (loads span the compute phase).
    if (t < 15) {
      STAGEB(nofs, (t + 1) * 64);
      WRITEA(nofs);                      // consumes Ar (k=(t+1)*64)
    }
    // 3) refill A regs for step t+2 (full iteration of latency cover).
    if (t < 14) LOADA((t + 2) * 64);

    // 4) compute step t.
#pragma unroll
    for (int kk = 0; kk < 2; ++kk)
#pragma unroll
      for (int i = 0; i < 4; ++i)
#pragma unroll
        for (int j = 0; j < 4; ++j)
          acc[i][j] = __builtin_amdgcn_mfma_f32_16x16x32_bf16(af[kk][i], bfr[kk][j],
                                                              acc[i][j], 0, 0, 0);

    // 5) single barrier: drains B gloads + A writes for t+1 (issued ~one full
    //    compute phase ago).
    __syncthreads();
  }
#undef LOADA
#undef STAGEB
#undef WRITEA

  // epilogue: verified C/D mapping: out row = quad*4 + r, out col = mrow.
  const int row_base = m0 + wr * 64 + quad * 4;
  const int col_base = n0 + wc * 64 + mrow;
#pragma unroll
  for (int i = 0; i < 4; ++i) {
#pragma unroll
    for (int j = 0; j < 4; ++j) {
#pragma unroll
      for (int r = 0; r < 4; ++r) {
        int row = row_base + i * 16 + r;
        Cb[(size_t)row * HID + col_base + j * 16] = f2bf(acc[i][j][r]);
      }
    }
  }
}

// ---- Kernel 3: RMS norm (proven; ~9 us, near its 7.6 us floor) ----
// out = C * 32 * rsqrt(sum C^2 + 400*eps*H) * norm_w   (/20 folded into scale)
__global__ __launch_bounds__(256) void rmsnorm_kernel(const unsigned short* __restrict__ Cb,
                                                      const float* __restrict__ nw,
                                                      float* __restrict__ out) {
  const int row = blockIdx.x * 4 + (threadIdx.x >> 6);
  const int lane = threadIdx.x & 63;
  const u16x8* src = reinterpret_cast<const u16x8*>(Cb) + (size_t)row * 128;
  f32x4 v[2][2];
  float ss = 0.f;
#pragma unroll
  for (int j = 0; j < 2; ++j) {
    u16x8 u = src[lane + j * 64];
#pragma unroll
    for (int h = 0; h < 2; ++h) {
#pragma unroll
      for (int e = 0; e < 4; ++e) {
        float f = bf2f(u[h * 4 + e]);
        v[j][h][e] = f;
        ss += f * f;
      }
    }
  }
#pragma unroll
  for (int off = 32; off > 0; off >>= 1) ss += __shfl_xor(ss, off, 64);
  const float scale = 32.0f * rsqrtf(ss + 0.4096f);  // 32=sqrt(H); 0.4096 = eps*H*400
  const f32x4* nwp = reinterpret_cast<const f32x4*>(nw);
  f32x4* dst = reinterpret_cast<f32x4*>(out) + (size_t)row * 256;
#pragma unroll
  for (int j = 0; j < 2; ++j) {
#pragma unroll
    for (int h = 0; h < 2; ++h) {
      const int fi = 2 * (lane + j * 64) + h;
      f32x4 wv = nwp[fi];
      f32x4 o = v[j][h] * scale * wv;
      __builtin_nontemporal_store(o, dst + fi);
    }
  }
}

extern "C" void kernel_launch(void* const* d_in, const int* in_sizes, int n_in,
                              void* d_out, int out_size, void* d_ws, size_t ws_size,
                              hipStream_t stream) {
  const float* x = (const float*)d_in[0];       // [2,4096,1024] fp32
  const float* conv_w = (const float*)d_in[1];  // [20,1024,1024] fp32
  const float* norm_w = (const float*)d_in[2];  // [1024] fp32
  float* out = (float*)d_out;                   // [2,4096,1024] fp32

  unsigned short* wb = (unsigned short*)d_ws;   // 2 MiB: summed W bf16 [N][K]
  unsigned short* cb = wb + (size_t)HID * HID;  // +16 MiB: C bf16

  wsum_kernel<<<512, 256, 0, stream>>>(conv_w, wb);
  gemm_kernel<<<(M_TOTAL / 128) * (HID / 128), 256, 0, stream>>>(x, wb, cb);
  rmsnorm_kernel<<<M_TOTAL / 4, 256, 0, stream>>>(cb, norm_w, out);
}